// Round 9
// baseline (1473.634 us; speedup 1.0000x reference)
//
#include <hip/hip_runtime.h>
#include <math.h>

// Problem constants (fixed by setup_inputs)
#define NN   32
#define SS   3200
#define CC   16
#define XLD  20      // row stride (floats) inside a 16x16 matrix slot
#define GSTR 328     // per-group matrix slot stride: bank offsets {0,8,16,24} across groups
#define D0   136     // C*(C+1)/2
#define DD   152     // D0 + k
#define SQRT2F 1.41421356237309515f
// SW_PASS 3: validated R4 (absmax 9.77e-3, passes; 3.8e-2 is known-fail).
// Do NOT drop to 2 — Jacobi residual would jump 5-20x through the tolerance.
#define SW_PASS 3
// SW_SMALL 6: validated R7 (absmax unchanged).
#define SW_SMALL 6

typedef float f2 __attribute__((ext_vector_type(2)));
__device__ __forceinline__ f2 mk2(float x, float y) { f2 r; r.x = x; r.y = y; return r; }

#define PHASE __builtin_amdgcn_sched_barrier(0)

// ---------------- cross-lane xor within 16-lane groups ----------------
//  P=0 (all-DPP): best for tiny latency-bound chains (DPP latency << swizzle).
//  P=1 (R0 policy): {1,2,3,7,8,15} single DPP, composites via ds_swizzle.
template<int M> __device__ __forceinline__ float lxor_dpp(float x) {
  if constexpr (M == 4)       return lxor_dpp<3>(lxor_dpp<7>(x));
  else if constexpr (M == 5)  return lxor_dpp<2>(lxor_dpp<7>(x));
  else if constexpr (M == 6)  return lxor_dpp<1>(lxor_dpp<7>(x));
  else if constexpr (M == 9)  return lxor_dpp<1>(lxor_dpp<8>(x));
  else if constexpr (M == 10) return lxor_dpp<2>(lxor_dpp<8>(x));
  else if constexpr (M == 11) return lxor_dpp<3>(lxor_dpp<8>(x));
  else if constexpr (M == 12) return lxor_dpp<3>(lxor_dpp<15>(x));
  else if constexpr (M == 13) return lxor_dpp<2>(lxor_dpp<15>(x));
  else if constexpr (M == 14) return lxor_dpp<1>(lxor_dpp<15>(x));
  else {
    int v = __float_as_int(x);
    int r;
    if      constexpr (M == 1)  r = __builtin_amdgcn_update_dpp(0, v, 0xB1, 0xF, 0xF, true);  // quad_perm [1,0,3,2]
    else if constexpr (M == 2)  r = __builtin_amdgcn_update_dpp(0, v, 0x4E, 0xF, 0xF, true);  // quad_perm [2,3,0,1]
    else if constexpr (M == 3)  r = __builtin_amdgcn_update_dpp(0, v, 0x1B, 0xF, 0xF, true);  // quad_perm [3,2,1,0]
    else if constexpr (M == 7)  r = __builtin_amdgcn_update_dpp(0, v, 0x141, 0xF, 0xF, true); // row_half_mirror
    else if constexpr (M == 8)  r = __builtin_amdgcn_update_dpp(0, v, 0x128, 0xF, 0xF, true); // row_ror:8
    else                        r = __builtin_amdgcn_update_dpp(0, v, 0x140, 0xF, 0xF, true); // row_mirror (15)
    return __int_as_float(r);
  }
}

template<int M, int P> __device__ __forceinline__ float lx(float x) {
  if constexpr (P == 1 && !(M == 1 || M == 2 || M == 3 || M == 7 || M == 8 || M == 15)) {
    int r = __builtin_amdgcn_ds_swizzle(__float_as_int(x), 0x1F | (M << 10)); // BitMode xor
    return __int_as_float(r);
  } else {
    return lxor_dpp<M>(x);
  }
}

// ---------------- one-sided Jacobi round: pairs (i, i^M) ----------------
template<int M, int P>
__device__ __forceinline__ void js_round(f2 a[8], float& d, int c) {
  f2 part[8];
  #pragma unroll
  for (int r = 0; r < 8; ++r) {
    part[r].x = lx<M, P>(a[r].x);
    part[r].y = lx<M, P>(a[r].y);
  }
  float pd = lx<M, P>(d);
  f2 s0 = a[0] * part[0];
  f2 s1 = a[1] * part[1];
  f2 s2 = a[2] * part[2];
  f2 s3 = a[3] * part[3];
  s0 += a[4] * part[4];
  s1 += a[5] * part[5];
  s2 += a[6] * part[6];
  s3 += a[7] * part[7];
  f2 sv = (s0 + s1) + (s2 + s3);
  float apq = sv.x + sv.y;
  int partner = c ^ M;
  bool isp = c < partner;
  float app = isp ? d : pd;
  float aqq = isp ? pd : d;
  // NOTE: keep the rcp form — t = 1/(|θ|+√(θ²+1)). The algebraically-equal
  // √(θ²+1)−|θ| cancels catastrophically at large θ (absmax 3.8e-2 FAIL).
  float theta = (aqq - app) * 0.5f * __builtin_amdgcn_rcpf(apq);
  float t = copysignf(__builtin_amdgcn_rcpf(fabsf(theta) + __builtin_amdgcn_sqrtf(fmaf(theta, theta, 1.f))), theta);
  t = (apq == 0.f) ? 0.f : t;
  float cs = __builtin_amdgcn_rsqf(fmaf(t, t, 1.f));
  float sn = t * cs;
  float se = isp ? -sn : sn;
  f2 pcs = mk2(cs, cs);
  f2 pse = mk2(se, se);
  #pragma unroll
  for (int r = 0; r < 8; ++r) a[r] = pcs * a[r] + pse * part[r];
  d = isp ? (app - t * apq) : (aqq + t * apq);
}

template<int P>
__device__ __forceinline__ void js_sweep(f2 a[8], float& d, int c) {
  js_round<1, P>(a, d, c);  js_round<2, P>(a, d, c);  js_round<3, P>(a, d, c);
  js_round<4, P>(a, d, c);  js_round<5, P>(a, d, c);  js_round<6, P>(a, d, c);
  js_round<7, P>(a, d, c);  js_round<8, P>(a, d, c);  js_round<9, P>(a, d, c);
  js_round<10, P>(a, d, c); js_round<11, P>(a, d, c); js_round<12, P>(a, d, c);
  js_round<13, P>(a, d, c); js_round<14, P>(a, d, c); js_round<15, P>(a, d, c);
}

__device__ __forceinline__ float colnorm2(const f2 a[8]) {
  f2 s0 = a[0] * a[0], s1 = a[1] * a[1], s2 = a[2] * a[2], s3 = a[3] * a[3];
  s0 += a[4] * a[4]; s1 += a[5] * a[5]; s2 += a[6] * a[6]; s3 += a[7] * a[7];
  f2 s = (s0 + s1) + (s2 + s3);
  return s.x + s.y;
}

// a: column c of symmetric M (packed pairs). Exit: a = lam_c * v_c, d = lam_c^2.
template<int P>
__device__ __forceinline__ void jacobi_os(f2 a[8], float& d, int c, int sweeps) {
  d = colnorm2(a);
  #pragma unroll 1
  for (int s = 0; s < sweeps; ++s) js_sweep<P>(a, d, c);
  d = colnorm2(a);
}

// ---------------- row dot: dot(M_row, v) ----------------
__device__ __forceinline__ float dotrow(const float* __restrict__ row, const f2 v[8]) {
  const float4 q0 = *(const float4*)(row + 0);
  const float4 q1 = *(const float4*)(row + 4);
  const float4 q2 = *(const float4*)(row + 8);
  const float4 q3 = *(const float4*)(row + 12);
  f2 s0 = mk2(q0.x, q0.y) * v[0] + mk2(q0.z, q0.w) * v[1];
  f2 s1 = mk2(q1.x, q1.y) * v[2] + mk2(q1.z, q1.w) * v[3];
  s0 += mk2(q2.x, q2.y) * v[4] + mk2(q2.z, q2.w) * v[5];
  s1 += mk2(q3.x, q3.y) * v[6] + mk2(q3.z, q3.w) * v[7];
  f2 s = s0 + s1;
  return s.x + s.y;
}

// y = Mat(16x16, LDS rows stride S) * v  (v, y packed by row pairs)
template<int S>
__device__ __forceinline__ void mv_lds(const float* __restrict__ M, const f2 v[8], f2 y[8]) {
  #pragma unroll
  for (int k = 0; k < 8; ++k) {
    float r0 = dotrow(M + (2 * k) * S, v);
    float r1 = dotrow(M + (2 * k + 1) * S, v);
    y[k] = mk2(r0, r1);
  }
}

// out (packed rows) = col c of Sum_i gb[i] * b_i b_i^T ; B row i = b_i (row stride S)
template<int S>
__device__ __forceinline__ void recon16(const float* __restrict__ B, const float* __restrict__ gb,
                                        int c, f2 o[8]) {
  #pragma unroll
  for (int k = 0; k < 8; ++k) o[k] = mk2(0.f, 0.f);
  #pragma unroll
  for (int i = 0; i < CC; ++i) {
    const float* row = B + i * S;
    float coef = gb[i] * row[c];
    f2 pc = mk2(coef, coef);
    const float4 q0 = *(const float4*)(row + 0);
    const float4 q1 = *(const float4*)(row + 4);
    const float4 q2 = *(const float4*)(row + 8);
    const float4 q3 = *(const float4*)(row + 12);
    o[0] += pc * mk2(q0.x, q0.y); o[1] += pc * mk2(q0.z, q0.w);
    o[2] += pc * mk2(q1.x, q1.y); o[3] += pc * mk2(q1.z, q1.w);
    o[4] += pc * mk2(q2.x, q2.y); o[5] += pc * mk2(q2.z, q2.w);
    o[6] += pc * mk2(q3.x, q3.y); o[7] += pc * mk2(q3.z, q3.w);
  }
}

template<int S>
__device__ __forceinline__ void recon2_16(const float* __restrict__ B, const float* __restrict__ g1,
                                          const float* __restrict__ g2, int c,
                                          f2 o1[8], f2 o2[8]) {
  #pragma unroll
  for (int k = 0; k < 8; ++k) { o1[k] = mk2(0.f, 0.f); o2[k] = mk2(0.f, 0.f); }
  #pragma unroll
  for (int i = 0; i < CC; ++i) {
    const float* row = B + i * S;
    float bic = row[c];
    f2 c1 = mk2(g1[i] * bic, g1[i] * bic);
    f2 c2 = mk2(g2[i] * bic, g2[i] * bic);
    const float4 q0 = *(const float4*)(row + 0);
    const float4 q1 = *(const float4*)(row + 4);
    const float4 q2 = *(const float4*)(row + 8);
    const float4 q3 = *(const float4*)(row + 12);
    f2 b0 = mk2(q0.x, q0.y), b1 = mk2(q0.z, q0.w), b2 = mk2(q1.x, q1.y), b3 = mk2(q1.z, q1.w);
    f2 b4 = mk2(q2.x, q2.y), b5 = mk2(q2.z, q2.w), b6 = mk2(q3.x, q3.y), b7 = mk2(q3.z, q3.w);
    o1[0] += c1 * b0; o1[1] += c1 * b1; o1[2] += c1 * b2; o1[3] += c1 * b3;
    o1[4] += c1 * b4; o1[5] += c1 * b5; o1[6] += c1 * b6; o1[7] += c1 * b7;
    o2[0] += c2 * b0; o2[1] += c2 * b1; o2[2] += c2 * b2; o2[3] += c2 * b3;
    o2[4] += c2 * b4; o2[5] += c2 * b5; o2[6] += c2 * b6; o2[7] += c2 * b7;
  }
}

// stage 4 contiguous 16x16 matrices (1024 floats) from global into XLD/GSTR layout
__device__ __forceinline__ void stage4(const float* __restrict__ src, float* __restrict__ dst, int lid) {
  #pragma unroll
  for (int i = 0; i < 4; ++i) {
    int f = (i * 64 + lid) * 4;       // float index in the contiguous source
    int m = f >> 8, w = f & 255;      // matrix, within-matrix
    *(float4*)(dst + m * GSTR + (w >> 4) * XLD + (w & 15)) = *(const float4*)(src + f);
  }
}

__device__ __forceinline__ void store_rows(float* __restrict__ RBg, int c, const f2 a[8]) {
  #pragma unroll
  for (int i = 0; i < 4; ++i)
    *(float4*)(RBg + c * XLD + 4 * i) = make_float4(a[2 * i].x, a[2 * i].y, a[2 * i + 1].x, a[2 * i + 1].y);
}

__device__ __forceinline__ void load_pairs(const float* __restrict__ src, f2 a[8], float scale) {
  #pragma unroll
  for (int i = 0; i < 4; ++i) {
    float4 v = *(const float4*)(src + 4 * i);
    a[2 * i]     = mk2(v.x * scale, v.y * scale);
    a[2 * i + 1] = mk2(v.z * scale, v.w * scale);
  }
}

__device__ __forceinline__ void store_pairs_g(float* __restrict__ dst, const f2 a[8]) {
  #pragma unroll
  for (int i = 0; i < 4; ++i)
    *(float4*)(dst + 4 * i) = make_float4(a[2 * i].x, a[2 * i].y, a[2 * i + 1].x, a[2 * i + 1].y);
}

// ---------------- Step 1: rm accumulation (float4 loads + LDS pre-reduce) ----------------
__global__ __launch_bounds__(256) void rm_mean_kernel(const float* __restrict__ x, float* __restrict__ rmsum) {
  __shared__ __align__(16) float4 part[256];
  int n = blockIdx.y;
  int tid = threadIdx.x;
  long base = (long)n * SS * 256 + (long)blockIdx.x * 128 * 256 + tid * 4;
  float4 s = make_float4(0.f, 0.f, 0.f, 0.f);
  for (int i = 0; i < 32; ++i) {
    float4 v = *(const float4*)(x + base + (long)i * 1024);
    s.x += v.x; s.y += v.y; s.z += v.z; s.w += v.w;
  }
  part[tid] = s;
  __syncthreads();
  if (tid < 64) {
    float4 a = part[tid], b = part[tid + 64], c = part[tid + 128], d = part[tid + 192];
    float4 t;
    t.x = (a.x + b.x) + (c.x + d.x);
    t.y = (a.y + b.y) + (c.y + d.y);
    t.z = (a.z + b.z) + (c.z + d.z);
    t.w = (a.w + b.w) + (c.w + d.w);
    int o = tid * 4;
    atomicAdd(&rmsum[n * 256 + o],     t.x);
    atomicAdd(&rmsum[n * 256 + o + 1], t.y);
    atomicAdd(&rmsum[n * 256 + o + 2], t.z);
    atomicAdd(&rmsum[n * 256 + o + 3], t.w);
  }
}

// ---------------- Step 2: eigh(rm) -> sq,isq ; Wsq = expm(sym(W)/2) ----------------
__global__ __launch_bounds__(256) void eigh_rm_kernel(const float* __restrict__ rmsum, const float* __restrict__ Wg,
                                                      float* __restrict__ sqrm, float* __restrict__ isqrm,
                                                      float* __restrict__ wsqo) {
  __shared__ __align__(16) float lds[4 * 1440];
  int tid = threadIdx.x;
  int wv = tid >> 6, lid = tid & 63, g = lid >> 4, c = lid & 15;
  float* Wr = lds + wv * 1440;
  float* RB = Wr;                 // 4 x GSTR
  float* G1 = Wr + 4 * GSTR;      // 64
  float* G2 = Wr + 4 * GSTR + 64; // 64
  int gid_raw = blockIdx.x * 16 + wv * 4 + g;
  int gid = gid_raw > 32 ? 32 : gid_raw;
  f2 a[8];
  if (gid < 32) {
    load_pairs(rmsum + gid * 256 + c * 16, a, 1.f / (float)SS);
  } else {
    #pragma unroll
    for (int k = 0; k < 8; ++k) {
      a[k].x = 0.5f * (Wg[c * 16 + 2 * k]     + Wg[(2 * k) * 16 + c]);
      a[k].y = 0.5f * (Wg[c * 16 + 2 * k + 1] + Wg[(2 * k + 1) * 16 + c]);
    }
  }
  // Gershgorin shift (only applied to the possibly-indefinite W matrix)
  float rs = 0.f;
  #pragma unroll
  for (int k = 0; k < 8; ++k) rs += fabsf(a[k].x) + fabsf(a[k].y);
  rs = fmaxf(rs, lxor_dpp<1>(rs)); rs = fmaxf(rs, lxor_dpp<2>(rs));
  rs = fmaxf(rs, lxor_dpp<4>(rs)); rs = fmaxf(rs, lxor_dpp<8>(rs));
  float sig = (gid == 32) ? (rs + 0.001f) : 0.f;
  #pragma unroll
  for (int k = 0; k < 8; ++k) {
    a[k].x += (2 * k     == c) ? sig : 0.f;
    a[k].y += (2 * k + 1 == c) ? sig : 0.f;
  }
  float d;
  jacobi_os<0>(a, d, c, SW_SMALL);
  float g1c, g2c;
  if (gid < 32) {
    float sqd = __builtin_amdgcn_sqrtf(d);
    float qd  = __builtin_amdgcn_sqrtf(sqd);            // d^{1/4}
    g1c = qd * __builtin_amdgcn_rcpf(d);                // d^{-3/4}: sqrtm
    g2c = __builtin_amdgcn_rcpf(d * qd);                // d^{-5/4}: invsqrtm
  } else {
    float lam = __builtin_amdgcn_sqrtf(d);
    g1c = __expf(0.5f * (lam - sig)) * __builtin_amdgcn_rcpf(fmaxf(d, 1e-30f));
    g2c = 0.f;
  }
  float* RBg = RB + g * GSTR;
  store_rows(RBg, c, a);
  G1[g * 16 + c] = g1c;
  G2[g * 16 + c] = g2c;
  __builtin_amdgcn_wave_barrier();
  f2 o1[8], o2[8];
  recon2_16<XLD>(RBg, G1 + g * 16, G2 + g * 16, c, o1, o2);
  if (gid_raw < 32) {
    store_pairs_g(sqrm  + gid * 256 + c * 16, o1);
    store_pairs_g(isqrm + gid * 256 + c * 16, o2);
  } else if (gid_raw == 32) {
    store_pairs_g(wsqo + c * 16, o1);
  }
}

// ---------------- Step 3: pass 1 — sum_s logm(isq_rm X isq_rm) ----------------
#define WSZ1W (4 * GSTR + 64)   // per-wave: Xs + GB = 1376
__global__ __launch_bounds__(256) __attribute__((amdgpu_num_vgpr(128)))
void pass1_kernel(const float* __restrict__ x, const float* __restrict__ isqrm,
                  float* __restrict__ gtsum) {
  __shared__ __align__(16) float lds[4 * WSZ1W + XLD * 16 + 1024];
  int tid = threadIdx.x;
  int wv = tid >> 6, lid = tid & 63, g = lid >> 4, c = lid & 15;
  int n = blockIdx.y;
  int s_base = blockIdx.x * 16 + wv * 4;
  float* Wr  = lds + wv * WSZ1W;
  float* Xs  = Wr;                      // 4 x GSTR; reused as recon buf
  float* GB  = Wr + 4 * GSTR;           // 64
  float* ISQ = lds + 4 * WSZ1W;         // 16 x XLD (block-shared)
  float* red = lds + 4 * WSZ1W + XLD * 16; // 1024 (cross-wave reduce)
  stage4(x + ((long)n * SS + s_base) * 256, Xs, lid);
  const float* isqn = isqrm + n * 256;
  ISQ[(tid >> 4) * XLD + (tid & 15)] = isqn[tid];
  __syncthreads();
  PHASE;
  f2 mc[8], y[8], a[8];
  load_pairs(ISQ + c * XLD, mc, 1.f);
  mv_lds<XLD>(Xs + g * GSTR, mc, y);
  mv_lds<XLD>(ISQ, y, a);
  PHASE;
  float d;
  jacobi_os<1>(a, d, c, SW_PASS);
  PHASE;
  float gc = 0.5f * __logf(fmaxf(d, 1e-30f)) * __builtin_amdgcn_rcpf(d);
  float* RBg = Xs + g * GSTR;   // X is dead; reuse (per-wave buffer)
  store_rows(RBg, c, a);
  GB[g * 16 + c] = gc;
  __builtin_amdgcn_wave_barrier();
  PHASE;
  f2 out[8];
  recon16<XLD>(RBg, GB + g * 16, c, out);
  PHASE;
  #pragma unroll
  for (int k = 0; k < 8; ++k) {
    out[k].x += __shfl_xor(out[k].x, 16);
    out[k].y += __shfl_xor(out[k].y, 16);
  }
  #pragma unroll
  for (int k = 0; k < 8; ++k) {
    out[k].x += __shfl_xor(out[k].x, 32);
    out[k].y += __shfl_xor(out[k].y, 32);
  }
  if (g == 0) store_pairs_g(red + wv * 256 + c * 16, out);
  __syncthreads();
  float v = red[tid] + red[256 + tid] + red[512 + tid] + red[768 + tid];
  atomicAdd(&gtsum[n * 256 + tid], v);
}

// ---------------- Step 4: x_mean chain -> isq_m, lt_mean ----------------
#define WSZ4 (8 * GSTR + 128)   // 2752
__global__ __launch_bounds__(256) void mean_update_kernel(const float* __restrict__ gtsum, const float* __restrict__ sqrm,
                                                          float* __restrict__ isqm, float* __restrict__ ltmean) {
  __shared__ __align__(16) float lds[4 * WSZ4];
  int tid = threadIdx.x;
  int wv = tid >> 6, lid = tid & 63, g = lid >> 4, c = lid & 15;
  int n0 = blockIdx.x * 16 + wv * 4 + g;
  float* Wr = lds + wv * WSZ4;
  float* RB = Wr;                  // 4 x GSTR
  float* SQ = Wr + 4 * GSTR;       // 4 x GSTR
  float* G1 = Wr + 8 * GSTR;       // 64
  float* G2 = Wr + 8 * GSTR + 64;  // 64
  // ---- eigh(gt) (indefinite -> shift), expm ----
  f2 a[8];
  load_pairs(gtsum + n0 * 256 + c * 16, a, 1.f / (float)SS);
  float rs = 0.f;
  #pragma unroll
  for (int k = 0; k < 8; ++k) rs += fabsf(a[k].x) + fabsf(a[k].y);
  rs = fmaxf(rs, lxor_dpp<1>(rs)); rs = fmaxf(rs, lxor_dpp<2>(rs));
  rs = fmaxf(rs, lxor_dpp<4>(rs)); rs = fmaxf(rs, lxor_dpp<8>(rs));
  float sig = rs + 0.001f;
  #pragma unroll
  for (int k = 0; k < 8; ++k) {
    a[k].x += (2 * k     == c) ? sig : 0.f;
    a[k].y += (2 * k + 1 == c) ? sig : 0.f;
  }
  float d;
  jacobi_os<0>(a, d, c, SW_SMALL);
  float lam = __builtin_amdgcn_sqrtf(d);
  float gc = __expf(lam - sig) * __builtin_amdgcn_rcpf(fmaxf(d, 1e-30f));
  float* RBg = RB + g * GSTR;
  store_rows(RBg, c, a);
  G1[g * 16 + c] = gc;
  __builtin_amdgcn_wave_barrier();
  f2 e1[8];
  recon16<XLD>(RBg, G1 + g * 16, c, e1);
  // ---- stage sq_rm (4 consecutive n for this wave) ----
  stage4(sqrm + (blockIdx.x * 16 + wv * 4) * 256, SQ, lid);
  __builtin_amdgcn_wave_barrier();
  store_rows(RBg, c, e1);
  __builtin_amdgcn_wave_barrier();
  float* SQg = SQ + g * GSTR;
  f2 mc[8], y[8], a2[8];
  load_pairs(SQg + c * XLD, mc, 1.f);
  mv_lds<XLD>(RBg, mc, y);    // expm(gt) * sq_col
  mv_lds<XLD>(SQg, y, a2);    // sq * y -> col c of x_mean
  float d2;
  jacobi_os<0>(a2, d2, c, SW_SMALL);
  float sqd = __builtin_amdgcn_sqrtf(d2);
  float qd  = __builtin_amdgcn_sqrtf(sqd);
  float g1c = __builtin_amdgcn_rcpf(d2 * qd);                                  // d^{-5/4}: invsqrtm
  float g2c = 0.5f * __logf(fmaxf(d2, 1e-30f)) * __builtin_amdgcn_rcpf(d2);   // logm
  store_rows(RBg, c, a2);
  G1[g * 16 + c] = g1c;
  G2[g * 16 + c] = g2c;
  __builtin_amdgcn_wave_barrier();
  f2 o1[8], o2[8];
  recon2_16<XLD>(RBg, G1 + g * 16, G2 + g * 16, c, o1, o2);
  store_pairs_g(isqm + n0 * 256 + c * 16, o1);
  #pragma unroll
  for (int k = 0; k < 8; ++k) {
    int r0 = 2 * k, r1 = 2 * k + 1;
    if (r0 >= c) ltmean[n0 * D0 + (r0 * (r0 + 1) / 2) + c] = o2[k].x * ((r0 == c) ? 1.f : SQRT2F);
    if (r1 >= c) ltmean[n0 * D0 + (r1 * (r1 + 1) / 2) + c] = o2[k].y * ((r1 == c) ? 1.f : SQRT2F);
  }
}

// ---------------- Step 5: pass 2 — xc = tril(Wsq logm(isq_m X isq_m) Wsq) ----------------
#define WSZ2W (4 * GSTR + 64)   // per-wave: Xs + GB = 1376
__global__ __launch_bounds__(256) __attribute__((amdgpu_num_vgpr(128)))
void pass2_kernel(const float* __restrict__ x, const float* __restrict__ isqm,
                  const float* __restrict__ wsqg, float* __restrict__ xc) {
  __shared__ __align__(16) float lds[4 * WSZ2W + 2 * XLD * 16];
  int tid = threadIdx.x;
  int wv = tid >> 6, lid = tid & 63, g = lid >> 4, c = lid & 15;
  int n = blockIdx.y;
  int s_base = blockIdx.x * 16 + wv * 4;
  float* Wr  = lds + wv * WSZ2W;
  float* Xs  = Wr;                           // 4 x GSTR; reused as recon buf
  float* GB  = Wr + 4 * GSTR;                // 64
  float* ISQ = lds + 4 * WSZ2W;              // 16 x XLD (block-shared)
  float* WSQ = ISQ + XLD * 16;               // 16 x XLD (block-shared)
  stage4(x + ((long)n * SS + s_base) * 256, Xs, lid);
  const float* isqn = isqm + n * 256;
  int rr = tid >> 4, cc = tid & 15;
  ISQ[rr * XLD + cc] = isqn[tid];
  WSQ[rr * XLD + cc] = wsqg[tid];
  __syncthreads();
  PHASE;
  f2 mc[8], y[8], a[8];
  load_pairs(ISQ + c * XLD, mc, 1.f);
  mv_lds<XLD>(Xs + g * GSTR, mc, y);
  mv_lds<XLD>(ISQ, y, a);
  PHASE;
  float d;
  jacobi_os<1>(a, d, c, SW_PASS);
  PHASE;
  float gc = 0.5f * __logf(fmaxf(d, 1e-30f)) * __builtin_amdgcn_rcpf(d);
  f2 b[8];
  mv_lds<XLD>(WSQ, a, b);   // fold outer Wsq sandwich into the recon columns
  float* RBg = Xs + g * GSTR;   // per-wave buffer
  store_rows(RBg, c, b);
  GB[g * 16 + c] = gc;
  __builtin_amdgcn_wave_barrier();
  PHASE;
  f2 out[8];
  recon16<XLD>(RBg, GB + g * 16, c, out);
  PHASE;
  long ob = ((long)n * SS + s_base + g) * (long)D0;
  #pragma unroll
  for (int k = 0; k < 8; ++k) {
    int r0 = 2 * k, r1 = 2 * k + 1;
    if (r0 >= c) xc[ob + (r0 * (r0 + 1) / 2) + c] = out[k].x * ((r0 == c) ? 1.f : SQRT2F);
    if (r1 >= c) xc[ob + (r1 * (r1 + 1) / 2) + c] = out[k].y * ((r1 == c) ? 1.f : SQRT2F);
  }
}

// ---------------- Step 6: covariance SYRK — 64x64 tiles, 4x4 per-thread ----------------
#define KSPLIT 4
__global__ __launch_bounds__(256) void syrk_kernel(const float* __restrict__ xc, float* __restrict__ cov) {
  __shared__ float Ap[32][68];
  __shared__ float Bp[32][68];
  const int TI[6] = {0,0,0,1,1,2};
  const int TJ[6] = {0,1,2,1,2,2};
  int n = blockIdx.y;
  int ti = TI[blockIdx.x], tj = TJ[blockIdx.x];
  int split = blockIdx.z;
  int tid = threadIdx.x;
  int tx = tid & 15, ty = tid >> 4;
  float acc[4][4] = {{0.f}};
  const float* xb = xc + (long)n * SS * D0;
  int s_beg = split * (SS / KSPLIT);
  int s_end = s_beg + (SS / KSPLIT);
  for (int s0 = s_beg; s0 < s_end; s0 += 32) {
    #pragma unroll
    for (int i = 0; i < 2; ++i) {
      int idx = tid + i * 256;          // 0..511 (512 float4 per tile)
      int ss = idx >> 4;                // 0..31
      int c4 = (idx & 15) * 4;          // 0..60
      const float* row = xb + (long)(s0 + ss) * D0;
      int gi = ti * 64 + c4;
      int gj = tj * 64 + c4;
      float4 av = (gi + 4 <= D0) ? *(const float4*)(row + gi) : make_float4(0.f, 0.f, 0.f, 0.f);
      float4 bv = (gj + 4 <= D0) ? *(const float4*)(row + gj) : make_float4(0.f, 0.f, 0.f, 0.f);
      *(float4*)&Ap[ss][c4] = av;
      *(float4*)&Bp[ss][c4] = bv;
    }
    __syncthreads();
    #pragma unroll 8
    for (int ss = 0; ss < 32; ++ss) {
      float4 a4 = *(const float4*)&Ap[ss][ty * 4];
      float4 b4 = *(const float4*)&Bp[ss][tx * 4];
      acc[0][0] += a4.x * b4.x; acc[0][1] += a4.x * b4.y; acc[0][2] += a4.x * b4.z; acc[0][3] += a4.x * b4.w;
      acc[1][0] += a4.y * b4.x; acc[1][1] += a4.y * b4.y; acc[1][2] += a4.y * b4.z; acc[1][3] += a4.y * b4.w;
      acc[2][0] += a4.z * b4.x; acc[2][1] += a4.z * b4.y; acc[2][2] += a4.z * b4.z; acc[2][3] += a4.z * b4.w;
      acc[3][0] += a4.w * b4.x; acc[3][1] += a4.w * b4.y; acc[3][2] += a4.w * b4.z; acc[3][3] += a4.w * b4.w;
    }
    __syncthreads();
  }
  const float sc = 1.f / (float)(SS - 1);
  long base = (long)n * D0 * D0;
  #pragma unroll
  for (int r = 0; r < 4; ++r) {
    #pragma unroll
    for (int c = 0; c < 4; ++c) {
      int i = ti * 64 + ty * 4 + r;
      int j = tj * 64 + tx * 4 + c;
      if (i < D0 && j < D0) {
        float v = acc[r][c] * sc;
        atomicAdd(&cov[base + (long)i * D0 + j], v);
        if (ti != tj) atomicAdd(&cov[base + (long)j * D0 + i], v);
      }
    }
  }
}

// ---------------- Cholesky (triangular LDS storage, ONE sync per k) ----------------
// R4-measured-best form (R5 LESSON: no one-wave panel blocking — serial panel
// costs more than the barriers it saves; max parallel width per k-step).
// EMB=1 (chol<D0>): instead of materializing E = [[L,0],[ltmean,I]] and running
// a separate E@Rm GEMM, compute out = E@Rm directly in the epilogue (R8:
// launch-count reduction). Sum order is ascending k, skipped terms are exact
// zeros -> matches the old gemm bit-for-bit (fma contraction aside).
template<int D, int NORM, int EMB, int THREADS>
__global__ __launch_bounds__(THREADS) void chol_kernel(const float* __restrict__ in, long inStride,
                                                       float* __restrict__ out, long outStride, int outLd,
                                                       const float* __restrict__ ltmean,
                                                       const float* __restrict__ Rm) {
  __shared__ float As[D * (D + 1) / 2];
  __shared__ float diag[D];
  __shared__ float red[THREADS];
  __shared__ float vrow[D0];
  int b = blockIdx.x;
  int tid = threadIdx.x;
  const float* inp = in + (long)b * inStride;
  for (int idx = tid; idx < D * D; idx += THREADS) {
    int r = idx / D, c2 = idx % D;
    if (c2 <= r) As[(r * (r + 1) / 2) + c2] = inp[idx];
  }
  __syncthreads();
  if (NORM) {
    float p = 0.f;
    for (int i = tid; i < D; i += THREADS) p += As[(i * (i + 1) / 2) + i];
    red[tid] = p;
    __syncthreads();
    for (int off = THREADS / 2; off >= 1; off >>= 1) {
      if (tid < off) red[tid] += red[tid + off];
      __syncthreads();
    }
    float inv = 1.f / red[0];
    for (int idx = tid; idx < D * (D + 1) / 2; idx += THREADS) As[idx] *= inv;
    __syncthreads();
    for (int i = tid; i < D; i += THREADS) As[(i * (i + 1) / 2) + i] += 1e-5f;
    __syncthreads();
  }
  const int TY = THREADS / 16;
  int tx = tid & 15, ty = tid >> 4;
  for (int k = 0; k < D; ++k) {
    float dkk = As[(k * (k + 1) / 2) + k];
    float invd = 1.f / dkk;
    if (tid == 0) diag[k] = dkk;
    for (int i = k + 1 + ty; i < D; i += TY) {
      float aik = As[(i * (i + 1) / 2) + k] * invd;
      int ibase = i * (i + 1) / 2;
      for (int j = k + 1 + tx; j <= i; j += 16) {
        As[ibase + j] -= aik * As[(j * (j + 1) / 2) + k];
      }
    }
    __syncthreads();
  }
  // column scales: red[c] = 1/sqrt(diag[c])
  for (int i = tid; i < D; i += THREADS) red[i] = 1.f / sqrtf(diag[i]);
  __syncthreads();
  float* op = out + (long)b * outStride;
  if (!EMB) {
    for (int idx = tid; idx < D * D; idx += THREADS) {
      int r = idx / D, c2 = idx % D;
      if (c2 < r)       op[r * outLd + c2] = As[(r * (r + 1) / 2) + c2] * red[c2];
      else if (c2 == r) op[r * outLd + c2] = diag[r] * red[r];   // sqrt(dkk)
      else              op[r * outLd + c2] = 0.f;                // upper triangle
    }
  } else {
    // ---- fused out = E @ Rm (E = [[L,0],[ltmean,I]]; Rm lower-tri, upper=0) ----
    const float* ltm = ltmean + b * D0;
    // vrow[j] = sum_{k} ltmean[k] * Rm[k,j]  (full k range; Rm upper zeros are exact no-ops)
    for (int j = tid; j < D0; j += THREADS) {
      float acc = 0.f;
      for (int k = 0; k < D0; ++k) acc = fmaf(ltm[k], Rm[k * DD + j], acc);
      vrow[j] = acc;
    }
    // rows r < D0: out[r,j] = sum_{k<=r} L[r,k]*Rm[k,j]  (j<=r), else 0
    for (int r = ty; r < D0; r += TY) {
      int rb = r * (r + 1) / 2;
      float dv = diag[r] * red[r];
      for (int j = tx; j < DD; j += 16) {
        float acc = 0.f;
        if (j <= r) {
          for (int k = 0; k < r; ++k) {
            float lv = As[rb + k] * red[k];
            acc = fmaf(lv, Rm[k * DD + j], acc);
          }
          acc = fmaf(dv, Rm[r * DD + j], acc);
        }
        op[r * DD + j] = acc;
      }
    }
    __syncthreads();
    // rows r >= D0: out[r,j] = vrow[j] (j<D0) + Rm[r,j]
    for (int idx = tid; idx < (DD - D0) * DD; idx += THREADS) {
      int r = D0 + idx / DD, j = idx % DD;
      float acc = (j < D0) ? vrow[j] : 0.f;
      acc += Rm[r * DD + j];   // Rm upper triangle stored as 0
      op[r * DD + j] = acc;
    }
  }
}

// ---------------- 152x152 GEMM: C = alpha*A@B (+I) ----------------
// psMode: B-element synthesized as Bq/24 + B2/120 + B3/720 (Paterson-Stockmeyer
//   Rq) and the epilogue adds Cd = I + Bq + B2/2 + B3/6.
// symA/symB (R8): operand synthesized on load as sym(Wlw)*0.125 — replaces the
//   wlw_prep kernel (exact pow2 scaling, bit-identical to the old Bm buffer).
__device__ __forceinline__ float bm_synth(const float* __restrict__ W, int r, int c) {
  return (W[r * DD + c] + W[c * DD + r]) * 0.125f;
}

__global__ __launch_bounds__(256) void gemm152_kernel(const float* __restrict__ A, long sA,
                                                      const float* __restrict__ B, float* __restrict__ Cm,
                                                      long sC, float alpha, int addI,
                                                      const float* __restrict__ B2,
                                                      const float* __restrict__ B3,
                                                      int psMode,
                                                      const float* __restrict__ WlwS,
                                                      int symA, int symB) {
  __shared__ float As[16][17];
  __shared__ float Bs[16][17];
  int b = blockIdx.y;
  const float* Ab_ = A + (long)b * sA;
  float* Cb = Cm + (long)b * sC;
  int tid = threadIdx.x;
  int tx = tid & 15, ty = tid >> 4;
  int row0 = (blockIdx.x / 10) * 16, col0 = (blockIdx.x % 10) * 16;
  float acc = 0.f;
  for (int k0 = 0; k0 < DD; k0 += 16) {
    int ar = row0 + ty, ac = k0 + tx;
    As[ty][tx] = (ar < DD && ac < DD) ? (symA ? bm_synth(WlwS, ar, ac) : Ab_[ar * DD + ac]) : 0.f;
    int br = k0 + ty, bc = col0 + tx;
    float bv = 0.f;
    if (br < DD && bc < DD) {
      if (psMode) {
        int bi = br * DD + bc;
        float bq = symB ? bm_synth(WlwS, br, bc) : B[bi];
        bv = bq * (1.f / 24.f) + B2[bi] * (1.f / 120.f) + B3[bi] * (1.f / 720.f);
      } else {
        bv = symB ? bm_synth(WlwS, br, bc) : B[br * DD + bc];
      }
    }
    Bs[ty][tx] = bv;
    __syncthreads();
    #pragma unroll
    for (int kk = 0; kk < 16; ++kk) acc += As[ty][kk] * Bs[kk][tx];
    __syncthreads();
  }
  int r = row0 + ty, c2 = col0 + tx;
  if (r < DD && c2 < DD) {
    float v = alpha * acc + ((addI && r == c2) ? 1.f : 0.f);
    if (psMode) {
      int ci = r * DD + c2;
      float bq = symB ? bm_synth(WlwS, r, c2) : B[ci];
      v += ((r == c2) ? 1.f : 0.f) + bq + B2[ci] * 0.5f + B3[ci] * (1.f / 6.f);
    }
    Cb[r * DD + c2] = v;
  }
}

extern "C" void kernel_launch(void* const* d_in, const int* in_sizes, int n_in,
                              void* d_out, int out_size, void* d_ws, size_t ws_size,
                              hipStream_t stream) {
  (void)in_sizes; (void)n_in; (void)out_size; (void)ws_size;
  const float* x   = (const float*)d_in[0];
  const float* W   = (const float*)d_in[1];
  const float* Wlw = (const float*)d_in[2];
  float* ws = (float*)d_ws;
  size_t off = 0;
  // R8: rmsum+gtsum+cov contiguous -> ONE memset covers all atomic targets.
  float* rmsum  = ws + off; off += 32 * 256;
  float* gtsum  = ws + off; off += 32 * 256;
  float* cov    = ws + off; off += (size_t)32 * D0 * D0;
  float* sqrm   = ws + off; off += 32 * 256;
  float* isqrm  = ws + off; off += 32 * 256;
  float* wsqb   = ws + off; off += 256;
  float* isqm   = ws + off; off += 32 * 256;
  float* ltmean = ws + off; off += 32 * D0;
  float* A2     = ws + off; off += DD * DD;
  float* A3     = ws + off; off += DD * DD;
  float* P1     = ws + off; off += DD * DD;
  float* P2     = ws + off; off += DD * DD;
  float* Rm     = ws + off; off += DD * DD;
  float* xcbuf  = ws + off; off += (size_t)32 * SS * D0;
  float* outp   = (float*)d_out;

  hipMemsetAsync(rmsum, 0, (size_t)(2 * 32 * 256 + 32 * D0 * D0) * sizeof(float), stream);

  rm_mean_kernel    <<<dim3(25, 32),  256, 0, stream>>>(x, rmsum);
  eigh_rm_kernel    <<<3,             256, 0, stream>>>(rmsum, W, sqrm, isqrm, wsqb);
  pass1_kernel      <<<dim3(200, 32), 256, 0, stream>>>(x, isqrm, gtsum);
  mean_update_kernel<<<2,             256, 0, stream>>>(gtsum, sqrm, isqm, ltmean);
  pass2_kernel      <<<dim3(200, 32), 256, 0, stream>>>(x, isqm, wsqb, xcbuf);
  syrk_kernel       <<<dim3(6, 32, KSPLIT), 256, 0, stream>>>(xcbuf, cov);

  // R = chol(expm(sym(W_lw))): scale 1/4, Paterson-Stockmeyer deg-6 (3 GEMMs,
  // ps_combo + wlw_prep fused in), square 2x. Runs before chol<D0> so the
  // E@Rm product can be fused into chol<D0>'s epilogue.
  gemm152_kernel  <<<dim3(100, 1), 256, 0, stream>>>(Wlw, 0L, nullptr, A2, 0L, 1.f, 0, nullptr, nullptr, 0, Wlw, 1, 1); // A2 = Bm^2 (Bm synth)
  gemm152_kernel  <<<dim3(100, 1), 256, 0, stream>>>(Wlw, 0L, A2,      A3, 0L, 1.f, 0, nullptr, nullptr, 0, Wlw, 1, 0); // A3 = Bm@A2
  gemm152_kernel  <<<dim3(100, 1), 256, 0, stream>>>(A3,  0L, nullptr, P1, 0L, 1.f, 0, A2, A3, 1, Wlw, 0, 1);           // P1 = expm(A/4) (PS fused)
  gemm152_kernel  <<<dim3(100, 1), 256, 0, stream>>>(P1,  0L, P1,      P2, 0L, 1.f, 0, nullptr, nullptr, 0, nullptr, 0, 0); // P2 = expm(A/2)
  gemm152_kernel  <<<dim3(100, 1), 256, 0, stream>>>(P2,  0L, P2,      P1, 0L, 1.f, 0, nullptr, nullptr, 0, nullptr, 0, 0); // P1 = expm(A)
  chol_kernel<DD, 0, 0, 1024><<<1, 1024, 0, stream>>>(P1, 0L, Rm, 0L, DD, nullptr, nullptr);

  // chol(cov) with fused out = E @ Rm epilogue (replaces E-build + final gemm)
  chol_kernel<D0, 1, 1, 256><<<32, 256, 0, stream>>>(cov, (long)D0 * D0, outp, (long)DD * DD, DD, ltmean, Rm);
}

// Round 10
// 1119.495 us; speedup vs baseline: 1.3163x; 1.3163x over previous
//
#include <hip/hip_runtime.h>
#include <math.h>

// Problem constants (fixed by setup_inputs)
#define NN   32
#define SS   3200
#define CC   16
#define XLD  20      // row stride (floats) inside a 16x16 matrix slot
#define GSTR 328     // per-group matrix slot stride: bank offsets {0,8,16,24} across groups
#define D0   136     // C*(C+1)/2
#define DD   152     // D0 + k
#define SQRT2F 1.41421356237309515f
// SW_PASS 3: validated R4 (absmax 9.77e-3, passes; 3.8e-2 is known-fail).
// Do NOT drop to 2 — Jacobi residual would jump 5-20x through the tolerance.
#define SW_PASS 3
// SW_SMALL 6: validated R7 (absmax unchanged).
#define SW_SMALL 6

typedef float f2 __attribute__((ext_vector_type(2)));
__device__ __forceinline__ f2 mk2(float x, float y) { f2 r; r.x = x; r.y = y; return r; }

#define PHASE __builtin_amdgcn_sched_barrier(0)

// ---------------- cross-lane xor within 16-lane groups ----------------
//  P=0 (all-DPP): best for tiny latency-bound chains (DPP latency << swizzle).
//  P=1 (R0 policy): {1,2,3,7,8,15} single DPP, composites via ds_swizzle.
template<int M> __device__ __forceinline__ float lxor_dpp(float x) {
  if constexpr (M == 4)       return lxor_dpp<3>(lxor_dpp<7>(x));
  else if constexpr (M == 5)  return lxor_dpp<2>(lxor_dpp<7>(x));
  else if constexpr (M == 6)  return lxor_dpp<1>(lxor_dpp<7>(x));
  else if constexpr (M == 9)  return lxor_dpp<1>(lxor_dpp<8>(x));
  else if constexpr (M == 10) return lxor_dpp<2>(lxor_dpp<8>(x));
  else if constexpr (M == 11) return lxor_dpp<3>(lxor_dpp<8>(x));
  else if constexpr (M == 12) return lxor_dpp<3>(lxor_dpp<15>(x));
  else if constexpr (M == 13) return lxor_dpp<2>(lxor_dpp<15>(x));
  else if constexpr (M == 14) return lxor_dpp<1>(lxor_dpp<15>(x));
  else {
    int v = __float_as_int(x);
    int r;
    if      constexpr (M == 1)  r = __builtin_amdgcn_update_dpp(0, v, 0xB1, 0xF, 0xF, true);  // quad_perm [1,0,3,2]
    else if constexpr (M == 2)  r = __builtin_amdgcn_update_dpp(0, v, 0x4E, 0xF, 0xF, true);  // quad_perm [2,3,0,1]
    else if constexpr (M == 3)  r = __builtin_amdgcn_update_dpp(0, v, 0x1B, 0xF, 0xF, true);  // quad_perm [3,2,1,0]
    else if constexpr (M == 7)  r = __builtin_amdgcn_update_dpp(0, v, 0x141, 0xF, 0xF, true); // row_half_mirror
    else if constexpr (M == 8)  r = __builtin_amdgcn_update_dpp(0, v, 0x128, 0xF, 0xF, true); // row_ror:8
    else                        r = __builtin_amdgcn_update_dpp(0, v, 0x140, 0xF, 0xF, true); // row_mirror (15)
    return __int_as_float(r);
  }
}

template<int M, int P> __device__ __forceinline__ float lx(float x) {
  if constexpr (P == 1 && !(M == 1 || M == 2 || M == 3 || M == 7 || M == 8 || M == 15)) {
    int r = __builtin_amdgcn_ds_swizzle(__float_as_int(x), 0x1F | (M << 10)); // BitMode xor
    return __int_as_float(r);
  } else {
    return lxor_dpp<M>(x);
  }
}

// ---------------- one-sided Jacobi round: pairs (i, i^M) ----------------
template<int M, int P>
__device__ __forceinline__ void js_round(f2 a[8], float& d, int c) {
  f2 part[8];
  #pragma unroll
  for (int r = 0; r < 8; ++r) {
    part[r].x = lx<M, P>(a[r].x);
    part[r].y = lx<M, P>(a[r].y);
  }
  float pd = lx<M, P>(d);
  f2 s0 = a[0] * part[0];
  f2 s1 = a[1] * part[1];
  f2 s2 = a[2] * part[2];
  f2 s3 = a[3] * part[3];
  s0 += a[4] * part[4];
  s1 += a[5] * part[5];
  s2 += a[6] * part[6];
  s3 += a[7] * part[7];
  f2 sv = (s0 + s1) + (s2 + s3);
  float apq = sv.x + sv.y;
  int partner = c ^ M;
  bool isp = c < partner;
  float app = isp ? d : pd;
  float aqq = isp ? pd : d;
  // NOTE: keep the rcp form — t = 1/(|θ|+√(θ²+1)). The algebraically-equal
  // √(θ²+1)−|θ| cancels catastrophically at large θ (absmax 3.8e-2 FAIL).
  float theta = (aqq - app) * 0.5f * __builtin_amdgcn_rcpf(apq);
  float t = copysignf(__builtin_amdgcn_rcpf(fabsf(theta) + __builtin_amdgcn_sqrtf(fmaf(theta, theta, 1.f))), theta);
  t = (apq == 0.f) ? 0.f : t;
  float cs = __builtin_amdgcn_rsqf(fmaf(t, t, 1.f));
  float sn = t * cs;
  float se = isp ? -sn : sn;
  f2 pcs = mk2(cs, cs);
  f2 pse = mk2(se, se);
  #pragma unroll
  for (int r = 0; r < 8; ++r) a[r] = pcs * a[r] + pse * part[r];
  d = isp ? (app - t * apq) : (aqq + t * apq);
}

template<int P>
__device__ __forceinline__ void js_sweep(f2 a[8], float& d, int c) {
  js_round<1, P>(a, d, c);  js_round<2, P>(a, d, c);  js_round<3, P>(a, d, c);
  js_round<4, P>(a, d, c);  js_round<5, P>(a, d, c);  js_round<6, P>(a, d, c);
  js_round<7, P>(a, d, c);  js_round<8, P>(a, d, c);  js_round<9, P>(a, d, c);
  js_round<10, P>(a, d, c); js_round<11, P>(a, d, c); js_round<12, P>(a, d, c);
  js_round<13, P>(a, d, c); js_round<14, P>(a, d, c); js_round<15, P>(a, d, c);
}

__device__ __forceinline__ float colnorm2(const f2 a[8]) {
  f2 s0 = a[0] * a[0], s1 = a[1] * a[1], s2 = a[2] * a[2], s3 = a[3] * a[3];
  s0 += a[4] * a[4]; s1 += a[5] * a[5]; s2 += a[6] * a[6]; s3 += a[7] * a[7];
  f2 s = (s0 + s1) + (s2 + s3);
  return s.x + s.y;
}

// a: column c of symmetric M (packed pairs). Exit: a = lam_c * v_c, d = lam_c^2.
template<int P>
__device__ __forceinline__ void jacobi_os(f2 a[8], float& d, int c, int sweeps) {
  d = colnorm2(a);
  #pragma unroll 1
  for (int s = 0; s < sweeps; ++s) js_sweep<P>(a, d, c);
  d = colnorm2(a);
}

// ---------------- row dot: dot(M_row, v) ----------------
__device__ __forceinline__ float dotrow(const float* __restrict__ row, const f2 v[8]) {
  const float4 q0 = *(const float4*)(row + 0);
  const float4 q1 = *(const float4*)(row + 4);
  const float4 q2 = *(const float4*)(row + 8);
  const float4 q3 = *(const float4*)(row + 12);
  f2 s0 = mk2(q0.x, q0.y) * v[0] + mk2(q0.z, q0.w) * v[1];
  f2 s1 = mk2(q1.x, q1.y) * v[2] + mk2(q1.z, q1.w) * v[3];
  s0 += mk2(q2.x, q2.y) * v[4] + mk2(q2.z, q2.w) * v[5];
  s1 += mk2(q3.x, q3.y) * v[6] + mk2(q3.z, q3.w) * v[7];
  f2 s = s0 + s1;
  return s.x + s.y;
}

// y = Mat(16x16, LDS rows stride S) * v  (v, y packed by row pairs)
template<int S>
__device__ __forceinline__ void mv_lds(const float* __restrict__ M, const f2 v[8], f2 y[8]) {
  #pragma unroll
  for (int k = 0; k < 8; ++k) {
    float r0 = dotrow(M + (2 * k) * S, v);
    float r1 = dotrow(M + (2 * k + 1) * S, v);
    y[k] = mk2(r0, r1);
  }
}

// out (packed rows) = col c of Sum_i gb[i] * b_i b_i^T ; B row i = b_i (row stride S)
template<int S>
__device__ __forceinline__ void recon16(const float* __restrict__ B, const float* __restrict__ gb,
                                        int c, f2 o[8]) {
  #pragma unroll
  for (int k = 0; k < 8; ++k) o[k] = mk2(0.f, 0.f);
  #pragma unroll
  for (int i = 0; i < CC; ++i) {
    const float* row = B + i * S;
    float coef = gb[i] * row[c];
    f2 pc = mk2(coef, coef);
    const float4 q0 = *(const float4*)(row + 0);
    const float4 q1 = *(const float4*)(row + 4);
    const float4 q2 = *(const float4*)(row + 8);
    const float4 q3 = *(const float4*)(row + 12);
    o[0] += pc * mk2(q0.x, q0.y); o[1] += pc * mk2(q0.z, q0.w);
    o[2] += pc * mk2(q1.x, q1.y); o[3] += pc * mk2(q1.z, q1.w);
    o[4] += pc * mk2(q2.x, q2.y); o[5] += pc * mk2(q2.z, q2.w);
    o[6] += pc * mk2(q3.x, q3.y); o[7] += pc * mk2(q3.z, q3.w);
  }
}

template<int S>
__device__ __forceinline__ void recon2_16(const float* __restrict__ B, const float* __restrict__ g1,
                                          const float* __restrict__ g2, int c,
                                          f2 o1[8], f2 o2[8]) {
  #pragma unroll
  for (int k = 0; k < 8; ++k) { o1[k] = mk2(0.f, 0.f); o2[k] = mk2(0.f, 0.f); }
  #pragma unroll
  for (int i = 0; i < CC; ++i) {
    const float* row = B + i * S;
    float bic = row[c];
    f2 c1 = mk2(g1[i] * bic, g1[i] * bic);
    f2 c2 = mk2(g2[i] * bic, g2[i] * bic);
    const float4 q0 = *(const float4*)(row + 0);
    const float4 q1 = *(const float4*)(row + 4);
    const float4 q2 = *(const float4*)(row + 8);
    const float4 q3 = *(const float4*)(row + 12);
    f2 b0 = mk2(q0.x, q0.y), b1 = mk2(q0.z, q0.w), b2 = mk2(q1.x, q1.y), b3 = mk2(q1.z, q1.w);
    f2 b4 = mk2(q2.x, q2.y), b5 = mk2(q2.z, q2.w), b6 = mk2(q3.x, q3.y), b7 = mk2(q3.z, q3.w);
    o1[0] += c1 * b0; o1[1] += c1 * b1; o1[2] += c1 * b2; o1[3] += c1 * b3;
    o1[4] += c1 * b4; o1[5] += c1 * b5; o1[6] += c1 * b6; o1[7] += c1 * b7;
    o2[0] += c2 * b0; o2[1] += c2 * b1; o2[2] += c2 * b2; o2[3] += c2 * b3;
    o2[4] += c2 * b4; o2[5] += c2 * b5; o2[6] += c2 * b6; o2[7] += c2 * b7;
  }
}

// stage 4 contiguous 16x16 matrices (1024 floats) from global into XLD/GSTR layout
__device__ __forceinline__ void stage4(const float* __restrict__ src, float* __restrict__ dst, int lid) {
  #pragma unroll
  for (int i = 0; i < 4; ++i) {
    int f = (i * 64 + lid) * 4;       // float index in the contiguous source
    int m = f >> 8, w = f & 255;      // matrix, within-matrix
    *(float4*)(dst + m * GSTR + (w >> 4) * XLD + (w & 15)) = *(const float4*)(src + f);
  }
}

__device__ __forceinline__ void store_rows(float* __restrict__ RBg, int c, const f2 a[8]) {
  #pragma unroll
  for (int i = 0; i < 4; ++i)
    *(float4*)(RBg + c * XLD + 4 * i) = make_float4(a[2 * i].x, a[2 * i].y, a[2 * i + 1].x, a[2 * i + 1].y);
}

__device__ __forceinline__ void load_pairs(const float* __restrict__ src, f2 a[8], float scale) {
  #pragma unroll
  for (int i = 0; i < 4; ++i) {
    float4 v = *(const float4*)(src + 4 * i);
    a[2 * i]     = mk2(v.x * scale, v.y * scale);
    a[2 * i + 1] = mk2(v.z * scale, v.w * scale);
  }
}

__device__ __forceinline__ void store_pairs_g(float* __restrict__ dst, const f2 a[8]) {
  #pragma unroll
  for (int i = 0; i < 4; ++i)
    *(float4*)(dst + 4 * i) = make_float4(a[2 * i].x, a[2 * i].y, a[2 * i + 1].x, a[2 * i + 1].y);
}

// ---------------- Step 1: rm accumulation (float4 loads + LDS pre-reduce) ----------------
__global__ __launch_bounds__(256) void rm_mean_kernel(const float* __restrict__ x, float* __restrict__ rmsum) {
  __shared__ __align__(16) float4 part[256];
  int n = blockIdx.y;
  int tid = threadIdx.x;
  long base = (long)n * SS * 256 + (long)blockIdx.x * 128 * 256 + tid * 4;
  float4 s = make_float4(0.f, 0.f, 0.f, 0.f);
  for (int i = 0; i < 32; ++i) {
    float4 v = *(const float4*)(x + base + (long)i * 1024);
    s.x += v.x; s.y += v.y; s.z += v.z; s.w += v.w;
  }
  part[tid] = s;
  __syncthreads();
  if (tid < 64) {
    float4 a = part[tid], b = part[tid + 64], c = part[tid + 128], d = part[tid + 192];
    float4 t;
    t.x = (a.x + b.x) + (c.x + d.x);
    t.y = (a.y + b.y) + (c.y + d.y);
    t.z = (a.z + b.z) + (c.z + d.z);
    t.w = (a.w + b.w) + (c.w + d.w);
    int o = tid * 4;
    atomicAdd(&rmsum[n * 256 + o],     t.x);
    atomicAdd(&rmsum[n * 256 + o + 1], t.y);
    atomicAdd(&rmsum[n * 256 + o + 2], t.z);
    atomicAdd(&rmsum[n * 256 + o + 3], t.w);
  }
}

// ---------------- Step 2: eigh(rm) -> sq,isq ; Wsq = expm(sym(W)/2) ----------------
__global__ __launch_bounds__(256) void eigh_rm_kernel(const float* __restrict__ rmsum, const float* __restrict__ Wg,
                                                      float* __restrict__ sqrm, float* __restrict__ isqrm,
                                                      float* __restrict__ wsqo) {
  __shared__ __align__(16) float lds[4 * 1440];
  int tid = threadIdx.x;
  int wv = tid >> 6, lid = tid & 63, g = lid >> 4, c = lid & 15;
  float* Wr = lds + wv * 1440;
  float* RB = Wr;                 // 4 x GSTR
  float* G1 = Wr + 4 * GSTR;      // 64
  float* G2 = Wr + 4 * GSTR + 64; // 64
  int gid_raw = blockIdx.x * 16 + wv * 4 + g;
  int gid = gid_raw > 32 ? 32 : gid_raw;
  f2 a[8];
  if (gid < 32) {
    load_pairs(rmsum + gid * 256 + c * 16, a, 1.f / (float)SS);
  } else {
    #pragma unroll
    for (int k = 0; k < 8; ++k) {
      a[k].x = 0.5f * (Wg[c * 16 + 2 * k]     + Wg[(2 * k) * 16 + c]);
      a[k].y = 0.5f * (Wg[c * 16 + 2 * k + 1] + Wg[(2 * k + 1) * 16 + c]);
    }
  }
  // Gershgorin shift (only applied to the possibly-indefinite W matrix)
  float rs = 0.f;
  #pragma unroll
  for (int k = 0; k < 8; ++k) rs += fabsf(a[k].x) + fabsf(a[k].y);
  rs = fmaxf(rs, lxor_dpp<1>(rs)); rs = fmaxf(rs, lxor_dpp<2>(rs));
  rs = fmaxf(rs, lxor_dpp<4>(rs)); rs = fmaxf(rs, lxor_dpp<8>(rs));
  float sig = (gid == 32) ? (rs + 0.001f) : 0.f;
  #pragma unroll
  for (int k = 0; k < 8; ++k) {
    a[k].x += (2 * k     == c) ? sig : 0.f;
    a[k].y += (2 * k + 1 == c) ? sig : 0.f;
  }
  float d;
  jacobi_os<0>(a, d, c, SW_SMALL);
  float g1c, g2c;
  if (gid < 32) {
    float sqd = __builtin_amdgcn_sqrtf(d);
    float qd  = __builtin_amdgcn_sqrtf(sqd);            // d^{1/4}
    g1c = qd * __builtin_amdgcn_rcpf(d);                // d^{-3/4}: sqrtm
    g2c = __builtin_amdgcn_rcpf(d * qd);                // d^{-5/4}: invsqrtm
  } else {
    float lam = __builtin_amdgcn_sqrtf(d);
    g1c = __expf(0.5f * (lam - sig)) * __builtin_amdgcn_rcpf(fmaxf(d, 1e-30f));
    g2c = 0.f;
  }
  float* RBg = RB + g * GSTR;
  store_rows(RBg, c, a);
  G1[g * 16 + c] = g1c;
  G2[g * 16 + c] = g2c;
  __builtin_amdgcn_wave_barrier();
  f2 o1[8], o2[8];
  recon2_16<XLD>(RBg, G1 + g * 16, G2 + g * 16, c, o1, o2);
  if (gid_raw < 32) {
    store_pairs_g(sqrm  + gid * 256 + c * 16, o1);
    store_pairs_g(isqrm + gid * 256 + c * 16, o2);
  } else if (gid_raw == 32) {
    store_pairs_g(wsqo + c * 16, o1);
  }
}

// ---------------- Step 3: pass 1 — sum_s logm(isq_rm X isq_rm) ----------------
#define WSZ1W (4 * GSTR + 64)   // per-wave: Xs + GB = 1376
__global__ __launch_bounds__(256) __attribute__((amdgpu_num_vgpr(128)))
void pass1_kernel(const float* __restrict__ x, const float* __restrict__ isqrm,
                  float* __restrict__ gtsum) {
  __shared__ __align__(16) float lds[4 * WSZ1W + XLD * 16 + 1024];
  int tid = threadIdx.x;
  int wv = tid >> 6, lid = tid & 63, g = lid >> 4, c = lid & 15;
  int n = blockIdx.y;
  int s_base = blockIdx.x * 16 + wv * 4;
  float* Wr  = lds + wv * WSZ1W;
  float* Xs  = Wr;                      // 4 x GSTR; reused as recon buf
  float* GB  = Wr + 4 * GSTR;           // 64
  float* ISQ = lds + 4 * WSZ1W;         // 16 x XLD (block-shared)
  float* red = lds + 4 * WSZ1W + XLD * 16; // 1024 (cross-wave reduce)
  stage4(x + ((long)n * SS + s_base) * 256, Xs, lid);
  const float* isqn = isqrm + n * 256;
  ISQ[(tid >> 4) * XLD + (tid & 15)] = isqn[tid];
  __syncthreads();
  PHASE;
  f2 mc[8], y[8], a[8];
  load_pairs(ISQ + c * XLD, mc, 1.f);
  mv_lds<XLD>(Xs + g * GSTR, mc, y);
  mv_lds<XLD>(ISQ, y, a);
  PHASE;
  float d;
  jacobi_os<1>(a, d, c, SW_PASS);
  PHASE;
  float gc = 0.5f * __logf(fmaxf(d, 1e-30f)) * __builtin_amdgcn_rcpf(d);
  float* RBg = Xs + g * GSTR;   // X is dead; reuse (per-wave buffer)
  store_rows(RBg, c, a);
  GB[g * 16 + c] = gc;
  __builtin_amdgcn_wave_barrier();
  PHASE;
  f2 out[8];
  recon16<XLD>(RBg, GB + g * 16, c, out);
  PHASE;
  #pragma unroll
  for (int k = 0; k < 8; ++k) {
    out[k].x += __shfl_xor(out[k].x, 16);
    out[k].y += __shfl_xor(out[k].y, 16);
  }
  #pragma unroll
  for (int k = 0; k < 8; ++k) {
    out[k].x += __shfl_xor(out[k].x, 32);
    out[k].y += __shfl_xor(out[k].y, 32);
  }
  if (g == 0) store_pairs_g(red + wv * 256 + c * 16, out);
  __syncthreads();
  float v = red[tid] + red[256 + tid] + red[512 + tid] + red[768 + tid];
  atomicAdd(&gtsum[n * 256 + tid], v);
}

// ---------------- Step 4: x_mean chain -> isq_m, lt_mean ----------------
#define WSZ4 (8 * GSTR + 128)   // 2752
__global__ __launch_bounds__(256) void mean_update_kernel(const float* __restrict__ gtsum, const float* __restrict__ sqrm,
                                                          float* __restrict__ isqm, float* __restrict__ ltmean) {
  __shared__ __align__(16) float lds[4 * WSZ4];
  int tid = threadIdx.x;
  int wv = tid >> 6, lid = tid & 63, g = lid >> 4, c = lid & 15;
  int n0 = blockIdx.x * 16 + wv * 4 + g;
  float* Wr = lds + wv * WSZ4;
  float* RB = Wr;                  // 4 x GSTR
  float* SQ = Wr + 4 * GSTR;       // 4 x GSTR
  float* G1 = Wr + 8 * GSTR;       // 64
  float* G2 = Wr + 8 * GSTR + 64;  // 64
  // ---- eigh(gt) (indefinite -> shift), expm ----
  f2 a[8];
  load_pairs(gtsum + n0 * 256 + c * 16, a, 1.f / (float)SS);
  float rs = 0.f;
  #pragma unroll
  for (int k = 0; k < 8; ++k) rs += fabsf(a[k].x) + fabsf(a[k].y);
  rs = fmaxf(rs, lxor_dpp<1>(rs)); rs = fmaxf(rs, lxor_dpp<2>(rs));
  rs = fmaxf(rs, lxor_dpp<4>(rs)); rs = fmaxf(rs, lxor_dpp<8>(rs));
  float sig = rs + 0.001f;
  #pragma unroll
  for (int k = 0; k < 8; ++k) {
    a[k].x += (2 * k     == c) ? sig : 0.f;
    a[k].y += (2 * k + 1 == c) ? sig : 0.f;
  }
  float d;
  jacobi_os<0>(a, d, c, SW_SMALL);
  float lam = __builtin_amdgcn_sqrtf(d);
  float gc = __expf(lam - sig) * __builtin_amdgcn_rcpf(fmaxf(d, 1e-30f));
  float* RBg = RB + g * GSTR;
  store_rows(RBg, c, a);
  G1[g * 16 + c] = gc;
  __builtin_amdgcn_wave_barrier();
  f2 e1[8];
  recon16<XLD>(RBg, G1 + g * 16, c, e1);
  // ---- stage sq_rm (4 consecutive n for this wave) ----
  stage4(sqrm + (blockIdx.x * 16 + wv * 4) * 256, SQ, lid);
  __builtin_amdgcn_wave_barrier();
  store_rows(RBg, c, e1);
  __builtin_amdgcn_wave_barrier();
  float* SQg = SQ + g * GSTR;
  f2 mc[8], y[8], a2[8];
  load_pairs(SQg + c * XLD, mc, 1.f);
  mv_lds<XLD>(RBg, mc, y);    // expm(gt) * sq_col
  mv_lds<XLD>(SQg, y, a2);    // sq * y -> col c of x_mean
  float d2;
  jacobi_os<0>(a2, d2, c, SW_SMALL);
  float sqd = __builtin_amdgcn_sqrtf(d2);
  float qd  = __builtin_amdgcn_sqrtf(sqd);
  float g1c = __builtin_amdgcn_rcpf(d2 * qd);                                  // d^{-5/4}: invsqrtm
  float g2c = 0.5f * __logf(fmaxf(d2, 1e-30f)) * __builtin_amdgcn_rcpf(d2);   // logm
  store_rows(RBg, c, a2);
  G1[g * 16 + c] = g1c;
  G2[g * 16 + c] = g2c;
  __builtin_amdgcn_wave_barrier();
  f2 o1[8], o2[8];
  recon2_16<XLD>(RBg, G1 + g * 16, G2 + g * 16, c, o1, o2);
  store_pairs_g(isqm + n0 * 256 + c * 16, o1);
  #pragma unroll
  for (int k = 0; k < 8; ++k) {
    int r0 = 2 * k, r1 = 2 * k + 1;
    if (r0 >= c) ltmean[n0 * D0 + (r0 * (r0 + 1) / 2) + c] = o2[k].x * ((r0 == c) ? 1.f : SQRT2F);
    if (r1 >= c) ltmean[n0 * D0 + (r1 * (r1 + 1) / 2) + c] = o2[k].y * ((r1 == c) ? 1.f : SQRT2F);
  }
}

// ---------------- Step 5: pass 2 — xc = tril(Wsq logm(isq_m X isq_m) Wsq) ----------------
#define WSZ2W (4 * GSTR + 64)   // per-wave: Xs + GB = 1376
__global__ __launch_bounds__(256) __attribute__((amdgpu_num_vgpr(128)))
void pass2_kernel(const float* __restrict__ x, const float* __restrict__ isqm,
                  const float* __restrict__ wsqg, float* __restrict__ xc) {
  __shared__ __align__(16) float lds[4 * WSZ2W + 2 * XLD * 16];
  int tid = threadIdx.x;
  int wv = tid >> 6, lid = tid & 63, g = lid >> 4, c = lid & 15;
  int n = blockIdx.y;
  int s_base = blockIdx.x * 16 + wv * 4;
  float* Wr  = lds + wv * WSZ2W;
  float* Xs  = Wr;                           // 4 x GSTR; reused as recon buf
  float* GB  = Wr + 4 * GSTR;                // 64
  float* ISQ = lds + 4 * WSZ2W;              // 16 x XLD (block-shared)
  float* WSQ = ISQ + XLD * 16;               // 16 x XLD (block-shared)
  stage4(x + ((long)n * SS + s_base) * 256, Xs, lid);
  const float* isqn = isqm + n * 256;
  int rr = tid >> 4, cc = tid & 15;
  ISQ[rr * XLD + cc] = isqn[tid];
  WSQ[rr * XLD + cc] = wsqg[tid];
  __syncthreads();
  PHASE;
  f2 mc[8], y[8], a[8];
  load_pairs(ISQ + c * XLD, mc, 1.f);
  mv_lds<XLD>(Xs + g * GSTR, mc, y);
  mv_lds<XLD>(ISQ, y, a);
  PHASE;
  float d;
  jacobi_os<1>(a, d, c, SW_PASS);
  PHASE;
  float gc = 0.5f * __logf(fmaxf(d, 1e-30f)) * __builtin_amdgcn_rcpf(d);
  f2 b[8];
  mv_lds<XLD>(WSQ, a, b);   // fold outer Wsq sandwich into the recon columns
  float* RBg = Xs + g * GSTR;   // per-wave buffer
  store_rows(RBg, c, b);
  GB[g * 16 + c] = gc;
  __builtin_amdgcn_wave_barrier();
  PHASE;
  f2 out[8];
  recon16<XLD>(RBg, GB + g * 16, c, out);
  PHASE;
  long ob = ((long)n * SS + s_base + g) * (long)D0;
  #pragma unroll
  for (int k = 0; k < 8; ++k) {
    int r0 = 2 * k, r1 = 2 * k + 1;
    if (r0 >= c) xc[ob + (r0 * (r0 + 1) / 2) + c] = out[k].x * ((r0 == c) ? 1.f : SQRT2F);
    if (r1 >= c) xc[ob + (r1 * (r1 + 1) / 2) + c] = out[k].y * ((r1 == c) ? 1.f : SQRT2F);
  }
}

// ---------------- Step 6: covariance SYRK — 64x64 tiles, 4x4 per-thread ----------------
#define KSPLIT 4
__global__ __launch_bounds__(256) void syrk_kernel(const float* __restrict__ xc, float* __restrict__ cov) {
  __shared__ float Ap[32][68];
  __shared__ float Bp[32][68];
  const int TI[6] = {0,0,0,1,1,2};
  const int TJ[6] = {0,1,2,1,2,2};
  int n = blockIdx.y;
  int ti = TI[blockIdx.x], tj = TJ[blockIdx.x];
  int split = blockIdx.z;
  int tid = threadIdx.x;
  int tx = tid & 15, ty = tid >> 4;
  float acc[4][4] = {{0.f}};
  const float* xb = xc + (long)n * SS * D0;
  int s_beg = split * (SS / KSPLIT);
  int s_end = s_beg + (SS / KSPLIT);
  for (int s0 = s_beg; s0 < s_end; s0 += 32) {
    #pragma unroll
    for (int i = 0; i < 2; ++i) {
      int idx = tid + i * 256;          // 0..511 (512 float4 per tile)
      int ss = idx >> 4;                // 0..31
      int c4 = (idx & 15) * 4;          // 0..60
      const float* row = xb + (long)(s0 + ss) * D0;
      int gi = ti * 64 + c4;
      int gj = tj * 64 + c4;
      float4 av = (gi + 4 <= D0) ? *(const float4*)(row + gi) : make_float4(0.f, 0.f, 0.f, 0.f);
      float4 bv = (gj + 4 <= D0) ? *(const float4*)(row + gj) : make_float4(0.f, 0.f, 0.f, 0.f);
      *(float4*)&Ap[ss][c4] = av;
      *(float4*)&Bp[ss][c4] = bv;
    }
    __syncthreads();
    #pragma unroll 8
    for (int ss = 0; ss < 32; ++ss) {
      float4 a4 = *(const float4*)&Ap[ss][ty * 4];
      float4 b4 = *(const float4*)&Bp[ss][tx * 4];
      acc[0][0] += a4.x * b4.x; acc[0][1] += a4.x * b4.y; acc[0][2] += a4.x * b4.z; acc[0][3] += a4.x * b4.w;
      acc[1][0] += a4.y * b4.x; acc[1][1] += a4.y * b4.y; acc[1][2] += a4.y * b4.z; acc[1][3] += a4.y * b4.w;
      acc[2][0] += a4.z * b4.x; acc[2][1] += a4.z * b4.y; acc[2][2] += a4.z * b4.z; acc[2][3] += a4.z * b4.w;
      acc[3][0] += a4.w * b4.x; acc[3][1] += a4.w * b4.y; acc[3][2] += a4.w * b4.z; acc[3][3] += a4.w * b4.w;
    }
    __syncthreads();
  }
  const float sc = 1.f / (float)(SS - 1);
  long base = (long)n * D0 * D0;
  #pragma unroll
  for (int r = 0; r < 4; ++r) {
    #pragma unroll
    for (int c = 0; c < 4; ++c) {
      int i = ti * 64 + ty * 4 + r;
      int j = tj * 64 + tx * 4 + c;
      if (i < D0 && j < D0) {
        float v = acc[r][c] * sc;
        atomicAdd(&cov[base + (long)i * D0 + j], v);
        if (ti != tj) atomicAdd(&cov[base + (long)j * D0 + i], v);
      }
    }
  }
}

// ---------------- Cholesky (triangular LDS storage, ONE sync per k) ----------------
// R4-measured-best form (R5 LESSON: no one-wave panel blocking; R9 LESSON: do
// NOT fuse the O(D0^3) E@Rm product into this 32-block kernel's epilogue — the
// scalar-global triangular loop ran at 1.8% VALU / 1.5% occupancy, 590us vs
// the separate 3200-block tiled GEMM's ~15us. Launch-count is worth ~15us;
// parallel structure is worth hundreds.)
// EMB=1: write L into the top-left of E and fill the E skeleton (cheap, R7 form).
template<int D, int NORM, int EMB, int THREADS>
__global__ __launch_bounds__(THREADS) void chol_kernel(const float* __restrict__ in, long inStride,
                                                       float* __restrict__ out, long outStride, int outLd,
                                                       const float* __restrict__ ltmean) {
  __shared__ float As[D * (D + 1) / 2];
  __shared__ float diag[D];
  __shared__ float red[THREADS];
  int b = blockIdx.x;
  int tid = threadIdx.x;
  const float* inp = in + (long)b * inStride;
  for (int idx = tid; idx < D * D; idx += THREADS) {
    int r = idx / D, c2 = idx % D;
    if (c2 <= r) As[(r * (r + 1) / 2) + c2] = inp[idx];
  }
  __syncthreads();
  if (NORM) {
    float p = 0.f;
    for (int i = tid; i < D; i += THREADS) p += As[(i * (i + 1) / 2) + i];
    red[tid] = p;
    __syncthreads();
    for (int off = THREADS / 2; off >= 1; off >>= 1) {
      if (tid < off) red[tid] += red[tid + off];
      __syncthreads();
    }
    float inv = 1.f / red[0];
    for (int idx = tid; idx < D * (D + 1) / 2; idx += THREADS) As[idx] *= inv;
    __syncthreads();
    for (int i = tid; i < D; i += THREADS) As[(i * (i + 1) / 2) + i] += 1e-5f;
    __syncthreads();
  }
  const int TY = THREADS / 16;
  int tx = tid & 15, ty = tid >> 4;
  for (int k = 0; k < D; ++k) {
    float dkk = As[(k * (k + 1) / 2) + k];
    float invd = 1.f / dkk;
    if (tid == 0) diag[k] = dkk;
    for (int i = k + 1 + ty; i < D; i += TY) {
      float aik = As[(i * (i + 1) / 2) + k] * invd;
      int ibase = i * (i + 1) / 2;
      for (int j = k + 1 + tx; j <= i; j += 16) {
        As[ibase + j] -= aik * As[(j * (j + 1) / 2) + k];
      }
    }
    __syncthreads();
  }
  // column scales: red[c] = 1/sqrt(diag[c])
  for (int i = tid; i < D; i += THREADS) red[i] = 1.f / sqrtf(diag[i]);
  __syncthreads();
  float* op = out + (long)b * outStride;
  for (int idx = tid; idx < D * D; idx += THREADS) {
    int r = idx / D, c2 = idx % D;
    if (c2 < r)       op[r * outLd + c2] = As[(r * (r + 1) / 2) + c2] * red[c2];
    else if (c2 == r) op[r * outLd + c2] = diag[r] * red[r];   // sqrt(dkk)
    else              op[r * outLd + c2] = 0.f;                // upper triangle
  }
  if (EMB) {
    // E skeleton: cols D0..DD-1 for rows<D0 are 0; rows D0..DD-1 = [ltmean | I_k]
    const float* ltm = ltmean + b * D0;
    for (int idx = tid; idx < D0 * (DD - D0); idx += THREADS) {
      int r = idx / (DD - D0), c2 = D0 + idx % (DD - D0);
      op[r * outLd + c2] = 0.f;
    }
    for (int idx = tid; idx < (DD - D0) * DD; idx += THREADS) {
      int r = D0 + idx / DD, c2 = idx % DD;
      op[r * outLd + c2] = (c2 < D0) ? ltm[c2] : ((r == c2) ? 1.f : 0.f);
    }
  }
}

// ---------------- 152x152 GEMM: C = alpha*A@B (+I) ----------------
// psMode: B-element synthesized as Bq/24 + B2/120 + B3/720 (Paterson-Stockmeyer
//   Rq) and the epilogue adds Cd = I + Bq + B2/2 + B3/6.
// symA/symB: operand synthesized on load as sym(Wlw)*0.125 (replaces wlw_prep;
//   exact pow2 scaling, bit-identical).
// triB: B lower-triangular with zeroed upper (Rm) — skip all-zero K-tiles.
__device__ __forceinline__ float bm_synth(const float* __restrict__ W, int r, int c) {
  return (W[r * DD + c] + W[c * DD + r]) * 0.125f;
}

__global__ __launch_bounds__(256) void gemm152_kernel(const float* __restrict__ A, long sA,
                                                      const float* __restrict__ B, float* __restrict__ Cm,
                                                      long sC, float alpha, int addI,
                                                      const float* __restrict__ B2,
                                                      const float* __restrict__ B3,
                                                      int psMode,
                                                      const float* __restrict__ WlwS,
                                                      int symA, int symB, int triB) {
  __shared__ float As[16][17];
  __shared__ float Bs[16][17];
  int b = blockIdx.y;
  const float* Ab_ = A + (long)b * sA;
  float* Cb = Cm + (long)b * sC;
  int tid = threadIdx.x;
  int tx = tid & 15, ty = tid >> 4;
  int row0 = (blockIdx.x / 10) * 16, col0 = (blockIdx.x % 10) * 16;
  float acc = 0.f;
  int k0beg = triB ? col0 : 0;
  for (int k0 = k0beg; k0 < DD; k0 += 16) {
    int ar = row0 + ty, ac = k0 + tx;
    As[ty][tx] = (ar < DD && ac < DD) ? (symA ? bm_synth(WlwS, ar, ac) : Ab_[ar * DD + ac]) : 0.f;
    int br = k0 + ty, bc = col0 + tx;
    float bv = 0.f;
    if (br < DD && bc < DD) {
      if (psMode) {
        int bi = br * DD + bc;
        float bq = symB ? bm_synth(WlwS, br, bc) : B[bi];
        bv = bq * (1.f / 24.f) + B2[bi] * (1.f / 120.f) + B3[bi] * (1.f / 720.f);
      } else {
        bv = symB ? bm_synth(WlwS, br, bc) : B[br * DD + bc];
      }
    }
    Bs[ty][tx] = bv;
    __syncthreads();
    #pragma unroll
    for (int kk = 0; kk < 16; ++kk) acc += As[ty][kk] * Bs[kk][tx];
    __syncthreads();
  }
  int r = row0 + ty, c2 = col0 + tx;
  if (r < DD && c2 < DD) {
    float v = alpha * acc + ((addI && r == c2) ? 1.f : 0.f);
    if (psMode) {
      int ci = r * DD + c2;
      float bq = symB ? bm_synth(WlwS, r, c2) : B[ci];
      v += ((r == c2) ? 1.f : 0.f) + bq + B2[ci] * 0.5f + B3[ci] * (1.f / 6.f);
    }
    Cb[r * DD + c2] = v;
  }
}

extern "C" void kernel_launch(void* const* d_in, const int* in_sizes, int n_in,
                              void* d_out, int out_size, void* d_ws, size_t ws_size,
                              hipStream_t stream) {
  (void)in_sizes; (void)n_in; (void)out_size; (void)ws_size;
  const float* x   = (const float*)d_in[0];
  const float* W   = (const float*)d_in[1];
  const float* Wlw = (const float*)d_in[2];
  float* ws = (float*)d_ws;
  size_t off = 0;
  // rmsum+gtsum+cov contiguous -> ONE memset covers all atomic targets.
  float* rmsum  = ws + off; off += 32 * 256;
  float* gtsum  = ws + off; off += 32 * 256;
  float* cov    = ws + off; off += (size_t)32 * D0 * D0;
  float* sqrm   = ws + off; off += 32 * 256;
  float* isqrm  = ws + off; off += 32 * 256;
  float* wsqb   = ws + off; off += 256;
  float* isqm   = ws + off; off += 32 * 256;
  float* ltmean = ws + off; off += 32 * D0;
  float* E      = ws + off; off += (size_t)32 * DD * DD;
  float* A2     = ws + off; off += DD * DD;
  float* A3     = ws + off; off += DD * DD;
  float* P1     = ws + off; off += DD * DD;
  float* P2     = ws + off; off += DD * DD;
  float* Rm     = ws + off; off += DD * DD;
  float* xcbuf  = ws + off; off += (size_t)32 * SS * D0;
  float* outp   = (float*)d_out;

  hipMemsetAsync(rmsum, 0, (size_t)(2 * 32 * 256 + 32 * D0 * D0) * sizeof(float), stream);

  rm_mean_kernel    <<<dim3(25, 32),  256, 0, stream>>>(x, rmsum);
  eigh_rm_kernel    <<<3,             256, 0, stream>>>(rmsum, W, sqrm, isqrm, wsqb);
  pass1_kernel      <<<dim3(200, 32), 256, 0, stream>>>(x, isqrm, gtsum);
  mean_update_kernel<<<2,             256, 0, stream>>>(gtsum, sqrm, isqm, ltmean);
  pass2_kernel      <<<dim3(200, 32), 256, 0, stream>>>(x, isqm, wsqb, xcbuf);
  syrk_kernel       <<<dim3(6, 32, KSPLIT), 256, 0, stream>>>(xcbuf, cov);
  chol_kernel<D0, 1, 1, 256><<<32, 256, 0, stream>>>(cov, (long)D0 * D0, E, (long)DD * DD, DD, ltmean);

  // R = chol(expm(sym(W_lw))): scale 1/4, Paterson-Stockmeyer deg-6 (3 GEMMs,
  // ps_combo + wlw_prep fused in), square 2x
  gemm152_kernel  <<<dim3(100, 1), 256, 0, stream>>>(Wlw, 0L, nullptr, A2, 0L, 1.f, 0, nullptr, nullptr, 0, Wlw, 1, 1, 0); // A2 = Bm^2 (Bm synth)
  gemm152_kernel  <<<dim3(100, 1), 256, 0, stream>>>(Wlw, 0L, A2,      A3, 0L, 1.f, 0, nullptr, nullptr, 0, Wlw, 1, 0, 0); // A3 = Bm@A2
  gemm152_kernel  <<<dim3(100, 1), 256, 0, stream>>>(A3,  0L, nullptr, P1, 0L, 1.f, 0, A2, A3, 1, Wlw, 0, 1, 0);           // P1 = expm(A/4) (PS fused)
  gemm152_kernel  <<<dim3(100, 1), 256, 0, stream>>>(P1,  0L, P1,      P2, 0L, 1.f, 0, nullptr, nullptr, 0, nullptr, 0, 0, 0); // P2 = expm(A/2)
  gemm152_kernel  <<<dim3(100, 1), 256, 0, stream>>>(P2,  0L, P2,      P1, 0L, 1.f, 0, nullptr, nullptr, 0, nullptr, 0, 0, 0); // P1 = expm(A)
  chol_kernel<DD, 0, 0, 1024><<<1, 1024, 0, stream>>>(P1, 0L, Rm, 0L, DD, nullptr);

  gemm152_kernel  <<<dim3(100, 32), 256, 0, stream>>>(E, (long)DD * DD, Rm, outp, (long)DD * DD, 1.f, 0, nullptr, nullptr, 0, nullptr, 0, 0, 1); // triB: Rm lower-tri
}